// Round 5
// baseline (3484.689 us; speedup 1.0000x reference)
//
#include <hip/hip_runtime.h>

#define EMB 64
constexpr int N_LAYERS = 3;
constexpr int OUT_D = EMB * (N_LAYERS + 1);  // 256
constexpr int SCAN_B = 256;
constexpr int BSHIFT = 13;  // 8192 rows per coarse bucket
constexpr int NBUK = 16;    // supports N <= 131072; col < 131072 (17 bits)

__device__ __forceinline__ float readlane_f(float v, int l) {
  return __int_as_float(__builtin_amdgcn_readlane(__float_as_int(v), l));
}
__device__ __forceinline__ int readlane_i(int v, int l) {
  return __builtin_amdgcn_readlane(v, l);
}
__device__ __forceinline__ int lanerank(unsigned long long m) {
  int r = __builtin_amdgcn_mbcnt_lo((unsigned)m, 0);
  return __builtin_amdgcn_mbcnt_hi((unsigned)(m >> 32), r);
}

// ego[r][d] = masked embedding; also writes block 0 of all_emb [N][256]
// NOTE: launched AFTER the CSR build because tmp aliases all_emb.
__global__ void init_ego_kernel(const float* __restrict__ ue, const float* __restrict__ ie,
                                const int* __restrict__ usz, const int* __restrict__ isz,
                                float* __restrict__ ego, float* __restrict__ all_emb,
                                int n_users, int n_total) {
  int idx = blockIdx.x * blockDim.x + threadIdx.x;
  if (idx >= n_total * EMB) return;
  int r = idx >> 6, d = idx & 63;
  float v; int sz;
  if (r < n_users) {
    v = ue[idx];
    sz = usz[r];
  } else {
    int ri = r - n_users;
    v = ie[ri * EMB + d];
    sz = isz[ri];
  }
  v = (d < sz) ? v : 0.0f;
  ego[idx] = v;
  all_emb[(size_t)r * OUT_D + d] = v;
}

// ---------- CSR build, two-level ----------

// coarse bucket histogram (16 buckets), register-accumulated
__global__ __launch_bounds__(256) void bucket_hist_kernel(const int* __restrict__ rows,
                                                          int* __restrict__ bcnt, int nnz) {
  int lc[NBUK];
#pragma unroll
  for (int b = 0; b < NBUK; ++b) lc[b] = 0;
  int i = blockIdx.x * blockDim.x + threadIdx.x;
  int stride = gridDim.x * blockDim.x;
  for (; i < nnz; i += stride) {
    int b = rows[i] >> BSHIFT;
#pragma unroll
    for (int bb = 0; bb < NBUK; ++bb) lc[bb] += (b == bb) ? 1 : 0;
  }
#pragma unroll
  for (int b = 0; b < NBUK; ++b) {
    int v = lc[b];
#pragma unroll
    for (int off = 32; off; off >>= 1) v += __shfl_xor(v, off, 64);
    if ((threadIdx.x & 63) == 0 && v) atomicAdd(&bcnt[b], v);
  }
}

__global__ void bucket_scan_kernel(const int* __restrict__ bcnt,
                                   int* __restrict__ bbase, int* __restrict__ bcursor) {
  if (threadIdx.x == 0 && blockIdx.x == 0) {
    int acc = 0;
    for (int b = 0; b < NBUK; ++b) {
      bbase[b] = acc;
      bcursor[b] = acc;
      acc += bcnt[b];
    }
    bbase[NBUK] = acc;
  }
}

// pass B: partition edges into 16 coarse bucket regions of tmp.
// wave-aggregated: per 256-edge wave-tile, one atomicAdd per bucket reserves a
// contiguous run; lanes write {val, (row_low<<17)|col} rank-ordered (run-grouped
// stores ~128B/bucket instead of one random line per edge).
__global__ __launch_bounds__(256) void partition_kernel(
    const float* __restrict__ vals, const int* __restrict__ rows,
    const int* __restrict__ cols, int* __restrict__ bcursor,
    int2* __restrict__ tmp, int nnz) {
  int lane = threadIdx.x & 63;
  int wtile = blockIdx.x * 4 + (threadIdx.x >> 6);
  int nwt = gridDim.x * 4;
  int ntiles = (nnz + 255) >> 8;
  for (int t = wtile; t < ntiles; t += nwt) {
    int base = t << 8;
    int rw[4], cl[4], bu[4];
    float vl[4];
#pragma unroll
    for (int u = 0; u < 4; ++u) {
      int ii = base + u * 64 + lane;
      bool ok = ii < nnz;
      rw[u] = ok ? rows[ii] : 0;
      cl[u] = ok ? cols[ii] : 0;
      vl[u] = ok ? vals[ii] : 0.0f;
      bu[u] = ok ? (rw[u] >> BSHIFT) : -1;
    }
#pragma unroll
    for (int b = 0; b < NBUK; ++b) {
      unsigned long long m[4];
      int c[4], tot = 0;
#pragma unroll
      for (int u = 0; u < 4; ++u) {
        m[u] = __ballot(bu[u] == b);
        c[u] = __popcll(m[u]);
        tot += c[u];
      }
      if (tot) {
        int gbase = 0;
        if (lane == 0) gbase = atomicAdd(&bcursor[b], tot);
        gbase = __shfl(gbase, 0, 64);
        int pre = 0;
#pragma unroll
        for (int u = 0; u < 4; ++u) {
          if (bu[u] == b) {
            int off = gbase + pre + lanerank(m[u]);
            tmp[off] = make_int2(__float_as_int(vl[u]),
                                 ((rw[u] & ((1 << BSHIFT) - 1)) << 17) | cl[u]);
          }
          pre += c[u];
        }
      }
    }
  }
}

// pass hist2: per-row counts, XCD-pinned (bucket = blockIdx&15 -> fixed XCD via %8
// round-robin) so atomics hit a 32KB L2-local counter slab.
__global__ __launch_bounds__(256) void hist2_kernel(const int2* __restrict__ tmp,
                                                    const int* __restrict__ bbase,
                                                    int* __restrict__ cnt) {
  int bucket = blockIdx.x & (NBUK - 1);
  int sub = blockIdx.x >> 4, nsub = gridDim.x >> 4;
  int s = bbase[bucket], e = bbase[bucket + 1];
  int rbase = bucket << BSHIFT;
  for (int i = s + sub * 256 + (int)threadIdx.x; i < e; i += nsub * 256) {
    int lr = ((unsigned)tmp[i].y) >> 17;
    atomicAdd(&cnt[rbase + lr], 1);
  }
}

// scans (unchanged)
__global__ __launch_bounds__(SCAN_B) void scan1_kernel(const int* __restrict__ cnt,
                                                       int* __restrict__ excl,
                                                       int* __restrict__ bsum,
                                                       int n, int M) {
  __shared__ int sm[SCAN_B];
  int t = threadIdx.x;
  int idx = blockIdx.x * SCAN_B + t;
  int x = (idx < n) ? cnt[idx] : 0;
  sm[t] = x;
  __syncthreads();
#pragma unroll
  for (int off = 1; off < SCAN_B; off <<= 1) {
    int y = (t >= off) ? sm[t - off] : 0;
    __syncthreads();
    sm[t] += y;
    __syncthreads();
  }
  if (idx < M) excl[idx] = sm[t] - x;
  if (t == SCAN_B - 1) bsum[blockIdx.x] = sm[t];
}

__global__ __launch_bounds__(512) void scan2_kernel(int* __restrict__ bsum, int nb) {
  __shared__ int sm[512];
  int t = threadIdx.x;
  int x = (t < nb) ? bsum[t] : 0;
  sm[t] = x;
  __syncthreads();
#pragma unroll
  for (int off = 1; off < 512; off <<= 1) {
    int y = (t >= off) ? sm[t - off] : 0;
    __syncthreads();
    sm[t] += y;
    __syncthreads();
  }
  if (t < nb) bsum[t] = sm[t] - x;
}

__global__ __launch_bounds__(SCAN_B) void scan3_kernel(int* __restrict__ excl,
                                                       const int* __restrict__ bsum,
                                                       int* __restrict__ cursor, int M) {
  int idx = blockIdx.x * SCAN_B + threadIdx.x;
  if (idx < M) {
    int v = excl[idx] + bsum[blockIdx.x];
    excl[idx] = v;
    cursor[idx] = v;
  }
}

// pass C: fine sort within bucket, XCD-pinned; random stores confined to the
// bucket's ~1.7MB region -> coalesce in the local L2 before eviction.
__global__ __launch_bounds__(256) void sort_fine_kernel(const int2* __restrict__ tmp,
                                                        const int* __restrict__ bbase,
                                                        int* __restrict__ cursor,
                                                        int2* __restrict__ edges) {
  int bucket = blockIdx.x & (NBUK - 1);
  int sub = blockIdx.x >> 4, nsub = gridDim.x >> 4;
  int s = bbase[bucket], e = bbase[bucket + 1];
  int rbase = bucket << BSHIFT;
  for (int i = s + sub * 256 + (int)threadIdx.x; i < e; i += nsub * 256) {
    int2 t = tmp[i];
    int lr = ((unsigned)t.y) >> 17;
    int col = t.y & 0x1FFFF;
    int p = atomicAdd(&cursor[rbase + lr], 1);
    edges[p] = make_int2(t.x, col);
  }
}

// ---------- atomic-free CSR SpMM: one wave per row, lane = dim ----------
__global__ __launch_bounds__(256) void spmm_csr_kernel(
    const int* __restrict__ rp, const int2* __restrict__ edges,
    const float* __restrict__ ego, float* __restrict__ side, int nrows) {
  int lane = threadIdx.x & 63;
  int r = blockIdx.x * (blockDim.x >> 6) + (threadIdx.x >> 6);
  if (r >= nrows) return;
  int start = rp[r], end = rp[r + 1];
  float acc = 0.0f;
  for (int base = start; base < end; base += 64) {
    int m = end - base;
    if (m > 64) m = 64;
    int2 e = (base + lane < end) ? edges[base + lane] : make_int2(0, 0);
    float v_l = __int_as_float(e.x);
    int c_l = e.y;
    int kk = 0;
    for (; kk + 8 <= m; kk += 8) {
      int c[8];
      float v[8], x[8];
#pragma unroll
      for (int u = 0; u < 8; ++u) {
        c[u] = readlane_i(c_l, kk + u);
        v[u] = readlane_f(v_l, kk + u);
      }
#pragma unroll
      for (int u = 0; u < 8; ++u) x[u] = ego[(size_t)c[u] * EMB + lane];
#pragma unroll
      for (int u = 0; u < 8; ++u) acc = fmaf(v[u], x[u], acc);
    }
    for (; kk < m; ++kk) {
      int c = readlane_i(c_l, kk);
      float v = readlane_f(v_l, kk);
      acc = fmaf(v, ego[(size_t)c * EMB + lane], acc);
    }
  }
  side[(size_t)r * EMB + lane] = acc;
}

__global__ __launch_bounds__(256) void layer_fused_kernel(
    const float* __restrict__ side, float* ego,
    const float* __restrict__ Wgc, const float* __restrict__ bgc,
    const float* __restrict__ Wbi, const float* __restrict__ bbi,
    float* __restrict__ all_emb, int nrows, int col_off) {
  int lane = threadIdx.x & 63;
  float wgc[EMB], wbi[EMB];
#pragma unroll
  for (int kk = 0; kk < EMB; ++kk) {
    wgc[kk] = Wgc[kk * EMB + lane];
    wbi[kk] = Wbi[kk * EMB + lane];
  }
  float bg = bgc[lane], bb = bbi[lane];
  int wid = blockIdx.x * (blockDim.x >> 6) + (threadIdx.x >> 6);
  int nw = gridDim.x * (blockDim.x >> 6);
  for (int r = wid; r < nrows; r += nw) {
    float s = side[(size_t)r * EMB + lane];
    float e = ego[(size_t)r * EMB + lane];
    float es = e * s;
    float accg = bg, accb = bb;
#pragma unroll
    for (int kk = 0; kk < EMB; ++kk) {
      accg = fmaf(readlane_f(s, kk), wgc[kk], accg);
      accb = fmaf(readlane_f(es, kk), wbi[kk], accb);
    }
    float o = accg + accb;
    o = (o >= 0.0f) ? o : 0.2f * o;
    ego[(size_t)r * EMB + lane] = o;
    float sq = o * o;
#pragma unroll
    for (int off = 32; off; off >>= 1) sq += __shfl_xor(sq, off, 64);
    float norm = fmaxf(sqrtf(sq), 1e-12f);
    all_emb[(size_t)r * OUT_D + col_off + lane] = o / norm;
  }
}

__global__ void gather_out_kernel(const float* __restrict__ all_emb,
                                  const int* __restrict__ users,
                                  const int* __restrict__ pos,
                                  const int* __restrict__ neg,
                                  float* __restrict__ out, int n_users, int B) {
  int row = blockIdx.x;
  int sec = blockIdx.y;
  int t = threadIdx.x;
  int src;
  if (sec == 0) src = users[row];
  else if (sec == 1) src = n_users + pos[row];
  else src = n_users + neg[row];
  out[((size_t)sec * B + row) * OUT_D + t] = all_emb[(size_t)src * OUT_D + t];
}

extern "C" void kernel_launch(void* const* d_in, const int* in_sizes, int n_in,
                              void* d_out, int out_size, void* d_ws, size_t ws_size,
                              hipStream_t stream) {
  const float* user_emb = (const float*)d_in[0];
  const float* item_emb = (const float*)d_in[1];
  const float* W_gc = (const float*)d_in[2];
  const float* b_gc = (const float*)d_in[3];
  const float* W_bi = (const float*)d_in[4];
  const float* b_bi = (const float*)d_in[5];
  const float* adj_vals = (const float*)d_in[6];
  const int* adj_rows = (const int*)d_in[7];
  const int* adj_cols = (const int*)d_in[8];
  const int* user_sizes = (const int*)d_in[9];
  const int* item_sizes = (const int*)d_in[10];
  const int* users = (const int*)d_in[11];
  const int* pos_items = (const int*)d_in[12];
  const int* neg_items = (const int*)d_in[13];

  const int n_users = in_sizes[9];
  const int n_items = in_sizes[10];
  const int N = n_users + n_items;
  const int nnz = in_sizes[6];
  const int B = in_sizes[11];
  const int M = N + 1;

  // workspace layout:
  // all_emb [N*256]f (tmp int2[nnz] aliases its first 8*nnz bytes during build)
  // | ego [N*64]f | side [N*64]f | row_ptr [M]i | cursor [M]i | bsum [512]i
  // | bcnt [16]i | bbase [17]i | bcursor [16]i | (align 8) edges [nnz]int2
  float* all_emb = (float*)d_ws;
  float* ego = all_emb + (size_t)N * OUT_D;
  float* side = ego + (size_t)N * EMB;
  int* row_ptr = (int*)(side + (size_t)N * EMB);
  int* cursor = row_ptr + M;
  int* bsum = cursor + M;
  int* bcnt = bsum + 512;
  int* bbase = bcnt + NBUK;
  int* bcursor = bbase + NBUK + 1;
  int2* edges = (int2*)((((uintptr_t)(bcursor + NBUK)) + 7) & ~(uintptr_t)7);
  int2* tmp = (int2*)all_emb;  // aliased; init_ego runs after the build

  // --- build CSR (two-level counting sort) ---
  hipMemsetAsync(bcnt, 0, NBUK * sizeof(int), stream);
  hipLaunchKernelGGL(bucket_hist_kernel, dim3(2048), dim3(256), 0, stream,
                     adj_rows, bcnt, nnz);
  hipLaunchKernelGGL(bucket_scan_kernel, dim3(1), dim3(64), 0, stream, bcnt,
                     bbase, bcursor);
  hipLaunchKernelGGL(partition_kernel, dim3(2048), dim3(256), 0, stream,
                     adj_vals, adj_rows, adj_cols, bcursor, tmp, nnz);
  hipMemsetAsync(cursor, 0, (size_t)M * sizeof(int), stream);
  hipLaunchKernelGGL(hist2_kernel, dim3(2048), dim3(256), 0, stream, tmp, bbase,
                     cursor);
  int nb = (M + SCAN_B - 1) / SCAN_B;
  hipLaunchKernelGGL(scan1_kernel, dim3(nb), dim3(SCAN_B), 0, stream, cursor,
                     row_ptr, bsum, N, M);
  hipLaunchKernelGGL(scan2_kernel, dim3(1), dim3(512), 0, stream, bsum, nb);
  hipLaunchKernelGGL(scan3_kernel, dim3(nb), dim3(SCAN_B), 0, stream, row_ptr,
                     bsum, cursor, M);
  hipLaunchKernelGGL(sort_fine_kernel, dim3(2048), dim3(256), 0, stream, tmp,
                     bbase, cursor, edges);

  // --- init ego + all_emb block 0 (after build: tmp aliased all_emb) ---
  {
    int total = N * EMB;
    hipLaunchKernelGGL(init_ego_kernel, dim3((total + 255) / 256), dim3(256), 0,
                       stream, user_emb, item_emb, user_sizes, item_sizes, ego,
                       all_emb, n_users, N);
  }

  // --- 3 propagation layers ---
  for (int k = 0; k < N_LAYERS; ++k) {
    hipLaunchKernelGGL(spmm_csr_kernel, dim3((N + 3) / 4), dim3(256), 0, stream,
                       row_ptr, edges, ego, side, N);
    hipLaunchKernelGGL(layer_fused_kernel, dim3(2048), dim3(256), 0, stream,
                       side, ego, W_gc + k * EMB * EMB, b_gc + k * EMB,
                       W_bi + k * EMB * EMB, b_bi + k * EMB, all_emb, N,
                       (k + 1) * EMB);
  }

  hipLaunchKernelGGL(gather_out_kernel, dim3(B, 3), dim3(256), 0, stream,
                     all_emb, users, pos_items, neg_items, (float*)d_out,
                     n_users, B);
}

// Round 6
// 3392.006 us; speedup vs baseline: 1.0273x; 1.0273x over previous
//
#include <hip/hip_runtime.h>

#define EMB 64
constexpr int N_LAYERS = 3;
constexpr int OUT_D = EMB * (N_LAYERS + 1);  // 256
constexpr int SUBR = 64;       // rows per bucket (LDS tile 64x64 f32 = 16KB)
constexpr int RSHIFT = 6;      // log2(SUBR)
constexpr int MAXBUK = 2048;   // supports N <= 131072
constexpr int PAD = 16;        // ints per counter line (64B) - kills line ping-pong
constexpr int CHUNK = 4096;    // edges per partition block
constexpr int EPT = CHUNK / 256;  // 16 edges/thread

__device__ __forceinline__ float readlane_f(float v, int l) {
  return __int_as_float(__builtin_amdgcn_readlane(__float_as_int(v), l));
}
__device__ __forceinline__ int readlane_i(int v, int l) {
  return __builtin_amdgcn_readlane(v, l);
}

// ego[r][d] = masked embedding; also writes block 0 of all_emb [N][256]
__global__ void init_ego_kernel(const float* __restrict__ ue, const float* __restrict__ ie,
                                const int* __restrict__ usz, const int* __restrict__ isz,
                                float* __restrict__ ego, float* __restrict__ all_emb,
                                int n_users, int n_total) {
  int idx = blockIdx.x * blockDim.x + threadIdx.x;
  if (idx >= n_total * EMB) return;
  int r = idx >> 6, d = idx & 63;
  float v; int sz;
  if (r < n_users) {
    v = ue[idx];
    sz = usz[r];
  } else {
    int ri = r - n_users;
    v = ie[ri * EMB + d];
    sz = isz[ri];
  }
  v = (d < sz) ? v : 0.0f;
  ego[idx] = v;
  all_emb[(size_t)r * OUT_D + d] = v;
}

// ---------- bucket histogram: LDS-aggregated, padded global flush ----------
__global__ __launch_bounds__(256) void bucket_hist_kernel(const int* __restrict__ rows,
                                                          int* __restrict__ bcnt_pad,
                                                          int nnz, int nbuk) {
  __shared__ int h[MAXBUK];
  for (int i = threadIdx.x; i < nbuk; i += 256) h[i] = 0;
  __syncthreads();
  int i = blockIdx.x * blockDim.x + threadIdx.x;
  int stride = gridDim.x * blockDim.x;
  for (; i < nnz; i += stride) atomicAdd(&h[rows[i] >> RSHIFT], 1);
  __syncthreads();
  for (int b = threadIdx.x; b < nbuk; b += 256)
    if (h[b]) atomicAdd(&bcnt_pad[b * PAD], h[b]);
}

// ---------- exclusive scan of padded counts -> bbase + padded cursors ----------
__global__ __launch_bounds__(512) void bucket_scan_kernel(const int* __restrict__ bcnt_pad,
                                                          int* __restrict__ bbase,
                                                          int* __restrict__ bcursor_pad,
                                                          int nbuk) {
  __shared__ int vals[MAXBUK];
  __shared__ int part[512];
  int t = threadIdx.x;
  for (int i = t; i < nbuk; i += 512) vals[i] = bcnt_pad[i * PAD];
  __syncthreads();
  int per = (nbuk + 511) / 512;
  int s0 = t * per;
  int lsum = 0;
  for (int i = 0; i < per; ++i) {
    int idx = s0 + i;
    if (idx < nbuk) lsum += vals[idx];
  }
  part[t] = lsum;
  __syncthreads();
  if (t == 0) {
    int acc = 0;
    for (int i = 0; i < 512; ++i) {
      int x = part[i];
      part[i] = acc;
      acc += x;
    }
  }
  __syncthreads();
  int run = part[t];
  for (int i = 0; i < per; ++i) {
    int idx = s0 + i;
    if (idx < nbuk) {
      bbase[idx] = run;
      bcursor_pad[idx * PAD] = run;
      run += vals[idx];
    }
  }
  if (t == 511) bbase[nbuk] = run;
}

// ---------- 3-phase LDS-staged partition ----------
// phase1: LDS histogram of this block's 4096 edges
// phase2: ONE padded global atomicAdd per (bucket, block) reserves a range
// phase3: rank via LDS cursor, write {val, (row_low<<17)|col} directly
__global__ __launch_bounds__(256) void partition_lds_kernel(
    const float* __restrict__ vals, const int* __restrict__ rows,
    const int* __restrict__ cols, int* __restrict__ bcursor_pad,
    int2* __restrict__ tmp, int nnz, int nbuk) {
  __shared__ int h[MAXBUK];
  __shared__ int cur[MAXBUK];
  for (int i = threadIdx.x; i < nbuk; i += 256) h[i] = 0;
  __syncthreads();

  int base = blockIdx.x * CHUNK;
  int rw[EPT], cl[EPT];
  float vl[EPT];
#pragma unroll
  for (int u = 0; u < EPT; ++u) {
    int ii = base + u * 256 + (int)threadIdx.x;
    bool ok = ii < nnz;
    rw[u] = ok ? rows[ii] : -1;
    cl[u] = ok ? cols[ii] : 0;
    vl[u] = ok ? vals[ii] : 0.0f;
    if (ok) atomicAdd(&h[rw[u] >> RSHIFT], 1);
  }
  __syncthreads();
  for (int b = threadIdx.x; b < nbuk; b += 256) {
    int c = h[b];
    cur[b] = c ? atomicAdd(&bcursor_pad[b * PAD], c) : 0;
  }
  __syncthreads();
#pragma unroll
  for (int u = 0; u < EPT; ++u) {
    if (rw[u] >= 0) {
      int b = rw[u] >> RSHIFT;
      int pos = atomicAdd(&cur[b], 1);
      tmp[pos] = make_int2(__float_as_int(vl[u]),
                           ((rw[u] & (SUBR - 1)) << 17) | cl[u]);
    }
  }
}

// ---------- SpMM: one block per 64-row bucket, LDS accumulator ----------
__global__ __launch_bounds__(256) void spmm_lds_kernel(
    const int* __restrict__ bbase, const int2* __restrict__ tmp,
    const float* __restrict__ ego, float* __restrict__ side, int nrows) {
  __shared__ float acc[SUBR * EMB];  // 16KB
  int b = blockIdx.x;
  int s = bbase[b], e = bbase[b + 1];
  for (int i = threadIdx.x; i < SUBR * EMB; i += 256) acc[i] = 0.0f;
  __syncthreads();
  int lane = threadIdx.x & 63;
  int w = threadIdx.x >> 6, nw = 4;
  for (int bs = s + w * 64; bs < e; bs += nw * 64) {
    int m = e - bs;
    if (m > 64) m = 64;
    int2 ed = (bs + lane < e) ? tmp[bs + lane] : make_int2(0, 0);
    float v_l = __int_as_float(ed.x);
    int p_l = ed.y;
    for (int kk = 0; kk < m; kk += 8) {
      int mm = m - kk;
      if (mm > 8) mm = 8;
      float x[8], vv[8];
      int rl[8];
      for (int u = 0; u < mm; ++u) {
        int pk = readlane_i(p_l, kk + u);
        vv[u] = readlane_f(v_l, kk + u);
        rl[u] = ((unsigned)pk) >> 17;
        x[u] = ego[(size_t)(pk & 0x1FFFF) * EMB + lane];
      }
      for (int u = 0; u < mm; ++u)
        atomicAdd(&acc[rl[u] * EMB + lane], vv[u] * x[u]);
    }
  }
  __syncthreads();
  int r0 = b << RSHIFT;
  for (int i = threadIdx.x; i < SUBR * EMB; i += 256) {
    int r = r0 + (i >> 6);
    if (r < nrows) side[(size_t)r * EMB + (i & 63)] = acc[i];
  }
}

// per row: sum_emb = side@Wgc + bgc ; bi = (ego*side)@Wbi + bbi ;
// ego_new = leaky_relu(sum+bi, 0.2) (stored UNNORMALIZED back into ego);
// all_emb[:, col_off:+64] = ego_new / max(||ego_new||, 1e-12)
__global__ __launch_bounds__(256) void layer_fused_kernel(
    const float* __restrict__ side, float* ego,
    const float* __restrict__ Wgc, const float* __restrict__ bgc,
    const float* __restrict__ Wbi, const float* __restrict__ bbi,
    float* __restrict__ all_emb, int nrows, int col_off) {
  int lane = threadIdx.x & 63;
  float wgc[EMB], wbi[EMB];
#pragma unroll
  for (int kk = 0; kk < EMB; ++kk) {
    wgc[kk] = Wgc[kk * EMB + lane];
    wbi[kk] = Wbi[kk * EMB + lane];
  }
  float bg = bgc[lane], bb = bbi[lane];
  int wid = blockIdx.x * (blockDim.x >> 6) + (threadIdx.x >> 6);
  int nw = gridDim.x * (blockDim.x >> 6);
  for (int r = wid; r < nrows; r += nw) {
    float s = side[(size_t)r * EMB + lane];
    float e = ego[(size_t)r * EMB + lane];
    float es = e * s;
    float accg = bg, accb = bb;
#pragma unroll
    for (int kk = 0; kk < EMB; ++kk) {
      accg = fmaf(readlane_f(s, kk), wgc[kk], accg);
      accb = fmaf(readlane_f(es, kk), wbi[kk], accb);
    }
    float o = accg + accb;
    o = (o >= 0.0f) ? o : 0.2f * o;
    ego[(size_t)r * EMB + lane] = o;
    float sq = o * o;
#pragma unroll
    for (int off = 32; off; off >>= 1) sq += __shfl_xor(sq, off, 64);
    float norm = fmaxf(sqrtf(sq), 1e-12f);
    all_emb[(size_t)r * OUT_D + col_off + lane] = o / norm;
  }
}

__global__ void gather_out_kernel(const float* __restrict__ all_emb,
                                  const int* __restrict__ users,
                                  const int* __restrict__ pos,
                                  const int* __restrict__ neg,
                                  float* __restrict__ out, int n_users, int B) {
  int row = blockIdx.x;
  int sec = blockIdx.y;
  int t = threadIdx.x;
  int src;
  if (sec == 0) src = users[row];
  else if (sec == 1) src = n_users + pos[row];
  else src = n_users + neg[row];
  out[((size_t)sec * B + row) * OUT_D + t] = all_emb[(size_t)src * OUT_D + t];
}

extern "C" void kernel_launch(void* const* d_in, const int* in_sizes, int n_in,
                              void* d_out, int out_size, void* d_ws, size_t ws_size,
                              hipStream_t stream) {
  const float* user_emb = (const float*)d_in[0];
  const float* item_emb = (const float*)d_in[1];
  const float* W_gc = (const float*)d_in[2];
  const float* b_gc = (const float*)d_in[3];
  const float* W_bi = (const float*)d_in[4];
  const float* b_bi = (const float*)d_in[5];
  const float* adj_vals = (const float*)d_in[6];
  const int* adj_rows = (const int*)d_in[7];
  const int* adj_cols = (const int*)d_in[8];
  const int* user_sizes = (const int*)d_in[9];
  const int* item_sizes = (const int*)d_in[10];
  const int* users = (const int*)d_in[11];
  const int* pos_items = (const int*)d_in[12];
  const int* neg_items = (const int*)d_in[13];

  const int n_users = in_sizes[9];
  const int n_items = in_sizes[10];
  const int N = n_users + n_items;
  const int nnz = in_sizes[6];
  const int B = in_sizes[11];
  const int nbuk = (N + SUBR - 1) / SUBR;  // 1563 for N=100000

  // workspace layout:
  // all_emb [N*256]f | ego [N*64]f | side [N*64]f | bbase [nbuk+1]i |
  // bcnt_pad [nbuk*PAD]i | bcursor_pad [nbuk*PAD]i | (align 8) edges [nnz]int2
  float* all_emb = (float*)d_ws;
  float* ego = all_emb + (size_t)N * OUT_D;
  float* side = ego + (size_t)N * EMB;
  int* bbase = (int*)(side + (size_t)N * EMB);
  int* bcnt_pad = bbase + (nbuk + 1);
  int* bcursor_pad = bcnt_pad + (size_t)nbuk * PAD;
  int2* edges = (int2*)((((uintptr_t)(bcursor_pad + (size_t)nbuk * PAD)) + 7) &
                        ~(uintptr_t)7);

  // --- init ego + all_emb block 0 ---
  {
    int total = N * EMB;
    hipLaunchKernelGGL(init_ego_kernel, dim3((total + 255) / 256), dim3(256), 0,
                       stream, user_emb, item_emb, user_sizes, item_sizes, ego,
                       all_emb, n_users, N);
  }

  // --- bucket partition (64-row buckets, no per-edge global atomics) ---
  hipMemsetAsync(bcnt_pad, 0, (size_t)nbuk * PAD * sizeof(int), stream);
  hipLaunchKernelGGL(bucket_hist_kernel, dim3(512), dim3(256), 0, stream,
                     adj_rows, bcnt_pad, nnz, nbuk);
  hipLaunchKernelGGL(bucket_scan_kernel, dim3(1), dim3(512), 0, stream,
                     bcnt_pad, bbase, bcursor_pad, nbuk);
  {
    int nchunks = (nnz + CHUNK - 1) / CHUNK;
    hipLaunchKernelGGL(partition_lds_kernel, dim3(nchunks), dim3(256), 0,
                       stream, adj_vals, adj_rows, adj_cols, bcursor_pad, edges,
                       nnz, nbuk);
  }

  // --- 3 propagation layers ---
  for (int k = 0; k < N_LAYERS; ++k) {
    hipLaunchKernelGGL(spmm_lds_kernel, dim3(nbuk), dim3(256), 0, stream, bbase,
                       edges, ego, side, N);
    hipLaunchKernelGGL(layer_fused_kernel, dim3(2048), dim3(256), 0, stream,
                       side, ego, W_gc + k * EMB * EMB, b_gc + k * EMB,
                       W_bi + k * EMB * EMB, b_bi + k * EMB, all_emb, N,
                       (k + 1) * EMB);
  }

  hipLaunchKernelGGL(gather_out_kernel, dim3(B, 3), dim3(256), 0, stream,
                     all_emb, users, pos_items, neg_items, (float*)d_out,
                     n_users, B);
}

// Round 7
// 706.280 us; speedup vs baseline: 4.9339x; 4.8026x over previous
//
#include <hip/hip_runtime.h>

#define EMB 64
constexpr int N_LAYERS = 3;
constexpr int OUT_D = EMB * (N_LAYERS + 1);  // 256
constexpr int SUBR = 64;       // rows per bucket
constexpr int RSHIFT = 6;      // log2(SUBR)
constexpr int MAXBUK = 2048;   // supports N <= 131072
constexpr int PAD = 16;        // ints per counter line (64B)
constexpr int CHUNK = 4096;    // edges per partition block
constexpr int EPT = CHUNK / 256;  // 16 edges/thread

__device__ __forceinline__ float readlane_f(float v, int l) {
  return __int_as_float(__builtin_amdgcn_readlane(__float_as_int(v), l));
}
__device__ __forceinline__ int readlane_i(int v, int l) {
  return __builtin_amdgcn_readlane(v, l);
}

// ego[r][d] = masked embedding; also writes block 0 of all_emb [N][256]
// NOTE: launched AFTER the CSR build because tmp aliases all_emb.
__global__ void init_ego_kernel(const float* __restrict__ ue, const float* __restrict__ ie,
                                const int* __restrict__ usz, const int* __restrict__ isz,
                                float* __restrict__ ego, float* __restrict__ all_emb,
                                int n_users, int n_total) {
  int idx = blockIdx.x * blockDim.x + threadIdx.x;
  if (idx >= n_total * EMB) return;
  int r = idx >> 6, d = idx & 63;
  float v; int sz;
  if (r < n_users) {
    v = ue[idx];
    sz = usz[r];
  } else {
    int ri = r - n_users;
    v = ie[ri * EMB + d];
    sz = isz[ri];
  }
  v = (d < sz) ? v : 0.0f;
  ego[idx] = v;
  all_emb[(size_t)r * OUT_D + d] = v;
}

// ---------- bucket histogram: LDS-aggregated, padded global flush ----------
__global__ __launch_bounds__(256) void bucket_hist_kernel(const int* __restrict__ rows,
                                                          int* __restrict__ bcnt_pad,
                                                          int nnz, int nbuk) {
  __shared__ int h[MAXBUK];
  for (int i = threadIdx.x; i < nbuk; i += 256) h[i] = 0;
  __syncthreads();
  int i = blockIdx.x * blockDim.x + threadIdx.x;
  int stride = gridDim.x * blockDim.x;
  for (; i < nnz; i += stride) atomicAdd(&h[rows[i] >> RSHIFT], 1);
  __syncthreads();
  for (int b = threadIdx.x; b < nbuk; b += 256)
    if (h[b]) atomicAdd(&bcnt_pad[b * PAD], h[b]);
}

// ---------- exclusive scan of padded counts -> bbase + padded cursors ----------
__global__ __launch_bounds__(512) void bucket_scan_kernel(const int* __restrict__ bcnt_pad,
                                                          int* __restrict__ bbase,
                                                          int* __restrict__ bcursor_pad,
                                                          int nbuk) {
  __shared__ int vals[MAXBUK];
  __shared__ int part[512];
  int t = threadIdx.x;
  for (int i = t; i < nbuk; i += 512) vals[i] = bcnt_pad[i * PAD];
  __syncthreads();
  int per = (nbuk + 511) / 512;
  int s0 = t * per;
  int lsum = 0;
  for (int i = 0; i < per; ++i) {
    int idx = s0 + i;
    if (idx < nbuk) lsum += vals[idx];
  }
  part[t] = lsum;
  __syncthreads();
  if (t == 0) {
    int acc = 0;
    for (int i = 0; i < 512; ++i) {
      int x = part[i];
      part[i] = acc;
      acc += x;
    }
  }
  __syncthreads();
  int run = part[t];
  for (int i = 0; i < per; ++i) {
    int idx = s0 + i;
    if (idx < nbuk) {
      bbase[idx] = run;
      bcursor_pad[idx * PAD] = run;
      run += vals[idx];
    }
  }
  if (t == 511) bbase[nbuk] = run;
}

// ---------- 3-phase LDS-staged partition into 64-row buckets ----------
__global__ __launch_bounds__(256) void partition_lds_kernel(
    const float* __restrict__ vals, const int* __restrict__ rows,
    const int* __restrict__ cols, int* __restrict__ bcursor_pad,
    int2* __restrict__ tmp, int nnz, int nbuk) {
  __shared__ int h[MAXBUK];
  __shared__ int cur[MAXBUK];
  for (int i = threadIdx.x; i < nbuk; i += 256) h[i] = 0;
  __syncthreads();

  int base = blockIdx.x * CHUNK;
  int rw[EPT], cl[EPT];
  float vl[EPT];
#pragma unroll
  for (int u = 0; u < EPT; ++u) {
    int ii = base + u * 256 + (int)threadIdx.x;
    bool ok = ii < nnz;
    rw[u] = ok ? rows[ii] : -1;
    cl[u] = ok ? cols[ii] : 0;
    vl[u] = ok ? vals[ii] : 0.0f;
    if (ok) atomicAdd(&h[rw[u] >> RSHIFT], 1);
  }
  __syncthreads();
  for (int b = threadIdx.x; b < nbuk; b += 256) {
    int c = h[b];
    cur[b] = c ? atomicAdd(&bcursor_pad[b * PAD], c) : 0;
  }
  __syncthreads();
#pragma unroll
  for (int u = 0; u < EPT; ++u) {
    if (rw[u] >= 0) {
      int b = rw[u] >> RSHIFT;
      int pos = atomicAdd(&cur[b], 1);
      tmp[pos] = make_int2(__float_as_int(vl[u]),
                           ((rw[u] & (SUBR - 1)) << 17) | cl[u]);
    }
  }
}

// ---------- per-bucket row sort -> final CSR (edges + row_ptr) ----------
// one block per bucket; LDS 64-counter count/scan/rank; writes confined to the
// bucket's contiguous ~13KB window. No global atomics.
__global__ __launch_bounds__(256) void bucket_sort_kernel(
    const int2* __restrict__ tmp, const int* __restrict__ bbase,
    int2* __restrict__ edges, int* __restrict__ row_ptr, int nrows) {
  __shared__ int h[SUBR];
  __shared__ int ex[SUBR + 1];
  int b = blockIdx.x;
  int s = bbase[b], e = bbase[b + 1];
  if (threadIdx.x < SUBR) h[threadIdx.x] = 0;
  __syncthreads();
  for (int i = s + (int)threadIdx.x; i < e; i += 256)
    atomicAdd(&h[((unsigned)tmp[i].y) >> 17], 1);
  __syncthreads();
  if (threadIdx.x == 0) {
    int acc = 0;
    for (int j = 0; j < SUBR; ++j) {
      ex[j] = acc;
      acc += h[j];
    }
    ex[SUBR] = acc;
  }
  __syncthreads();
  int r0 = b << RSHIFT;
  if (threadIdx.x <= SUBR) {
    int j = threadIdx.x;
    int r = r0 + j;
    if ((j < SUBR && r < nrows) || r == nrows) row_ptr[r] = s + ex[j];
  }
  if (threadIdx.x < SUBR) h[threadIdx.x] = ex[threadIdx.x];  // cursors
  __syncthreads();
  for (int i = s + (int)threadIdx.x; i < e; i += 256) {
    int2 t = tmp[i];
    int rl = ((unsigned)t.y) >> 17;
    int p = atomicAdd(&h[rl], 1);
    edges[s + p] = make_int2(t.x, t.y & 0x1FFFF);
  }
}

// ---------- atomic-free CSR SpMM: one wave per row, lane = dim ----------
__global__ __launch_bounds__(256) void spmm_csr_kernel(
    const int* __restrict__ rp, const int2* __restrict__ edges,
    const float* __restrict__ ego, float* __restrict__ side, int nrows) {
  int lane = threadIdx.x & 63;
  int r = blockIdx.x * (blockDim.x >> 6) + (threadIdx.x >> 6);
  if (r >= nrows) return;
  int start = rp[r], end = rp[r + 1];
  float acc = 0.0f;
  for (int base = start; base < end; base += 64) {
    int m = end - base;
    if (m > 64) m = 64;
    int2 e = (base + lane < end) ? edges[base + lane] : make_int2(0, 0);
    float v_l = __int_as_float(e.x);
    int c_l = e.y;
    int kk = 0;
    for (; kk + 8 <= m; kk += 8) {
      int c[8];
      float v[8], x[8];
#pragma unroll
      for (int u = 0; u < 8; ++u) {
        c[u] = readlane_i(c_l, kk + u);
        v[u] = readlane_f(v_l, kk + u);
      }
#pragma unroll
      for (int u = 0; u < 8; ++u) x[u] = ego[(size_t)c[u] * EMB + lane];
#pragma unroll
      for (int u = 0; u < 8; ++u) acc = fmaf(v[u], x[u], acc);
    }
    for (; kk < m; ++kk) {
      int c = readlane_i(c_l, kk);
      float v = readlane_f(v_l, kk);
      acc = fmaf(v, ego[(size_t)c * EMB + lane], acc);
    }
  }
  side[(size_t)r * EMB + lane] = acc;
}

__global__ __launch_bounds__(256) void layer_fused_kernel(
    const float* __restrict__ side, float* ego,
    const float* __restrict__ Wgc, const float* __restrict__ bgc,
    const float* __restrict__ Wbi, const float* __restrict__ bbi,
    float* __restrict__ all_emb, int nrows, int col_off) {
  int lane = threadIdx.x & 63;
  float wgc[EMB], wbi[EMB];
#pragma unroll
  for (int kk = 0; kk < EMB; ++kk) {
    wgc[kk] = Wgc[kk * EMB + lane];
    wbi[kk] = Wbi[kk * EMB + lane];
  }
  float bg = bgc[lane], bb = bbi[lane];
  int wid = blockIdx.x * (blockDim.x >> 6) + (threadIdx.x >> 6);
  int nw = gridDim.x * (blockDim.x >> 6);
  for (int r = wid; r < nrows; r += nw) {
    float s = side[(size_t)r * EMB + lane];
    float e = ego[(size_t)r * EMB + lane];
    float es = e * s;
    float accg = bg, accb = bb;
#pragma unroll
    for (int kk = 0; kk < EMB; ++kk) {
      accg = fmaf(readlane_f(s, kk), wgc[kk], accg);
      accb = fmaf(readlane_f(es, kk), wbi[kk], accb);
    }
    float o = accg + accb;
    o = (o >= 0.0f) ? o : 0.2f * o;
    ego[(size_t)r * EMB + lane] = o;
    float sq = o * o;
#pragma unroll
    for (int off = 32; off; off >>= 1) sq += __shfl_xor(sq, off, 64);
    float norm = fmaxf(sqrtf(sq), 1e-12f);
    all_emb[(size_t)r * OUT_D + col_off + lane] = o / norm;
  }
}

__global__ void gather_out_kernel(const float* __restrict__ all_emb,
                                  const int* __restrict__ users,
                                  const int* __restrict__ pos,
                                  const int* __restrict__ neg,
                                  float* __restrict__ out, int n_users, int B) {
  int row = blockIdx.x;
  int sec = blockIdx.y;
  int t = threadIdx.x;
  int src;
  if (sec == 0) src = users[row];
  else if (sec == 1) src = n_users + pos[row];
  else src = n_users + neg[row];
  out[((size_t)sec * B + row) * OUT_D + t] = all_emb[(size_t)src * OUT_D + t];
}

extern "C" void kernel_launch(void* const* d_in, const int* in_sizes, int n_in,
                              void* d_out, int out_size, void* d_ws, size_t ws_size,
                              hipStream_t stream) {
  const float* user_emb = (const float*)d_in[0];
  const float* item_emb = (const float*)d_in[1];
  const float* W_gc = (const float*)d_in[2];
  const float* b_gc = (const float*)d_in[3];
  const float* W_bi = (const float*)d_in[4];
  const float* b_bi = (const float*)d_in[5];
  const float* adj_vals = (const float*)d_in[6];
  const int* adj_rows = (const int*)d_in[7];
  const int* adj_cols = (const int*)d_in[8];
  const int* user_sizes = (const int*)d_in[9];
  const int* item_sizes = (const int*)d_in[10];
  const int* users = (const int*)d_in[11];
  const int* pos_items = (const int*)d_in[12];
  const int* neg_items = (const int*)d_in[13];

  const int n_users = in_sizes[9];
  const int n_items = in_sizes[10];
  const int N = n_users + n_items;
  const int nnz = in_sizes[6];
  const int B = in_sizes[11];
  const int nbuk = (N + SUBR - 1) / SUBR;  // 1563 for N=100000

  // workspace layout:
  // all_emb [N*256]f (tmp int2[nnz] aliases its head during build)
  // | ego [N*64]f | side [N*64]f | row_ptr [N+1]i | bbase [nbuk+1]i |
  // bcnt_pad [nbuk*PAD]i | bcursor_pad [nbuk*PAD]i | (align 8) edges [nnz]int2
  float* all_emb = (float*)d_ws;
  float* ego = all_emb + (size_t)N * OUT_D;
  float* side = ego + (size_t)N * EMB;
  int* row_ptr = (int*)(side + (size_t)N * EMB);
  int* bbase = row_ptr + (N + 1);
  int* bcnt_pad = bbase + (nbuk + 1);
  int* bcursor_pad = bcnt_pad + (size_t)nbuk * PAD;
  int2* edges = (int2*)((((uintptr_t)(bcursor_pad + (size_t)nbuk * PAD)) + 7) &
                        ~(uintptr_t)7);
  int2* tmp = (int2*)all_emb;  // aliased; init_ego runs after the build

  // --- build row-sorted CSR (bucket partition + per-bucket sort) ---
  hipMemsetAsync(bcnt_pad, 0, (size_t)nbuk * PAD * sizeof(int), stream);
  hipLaunchKernelGGL(bucket_hist_kernel, dim3(512), dim3(256), 0, stream,
                     adj_rows, bcnt_pad, nnz, nbuk);
  hipLaunchKernelGGL(bucket_scan_kernel, dim3(1), dim3(512), 0, stream,
                     bcnt_pad, bbase, bcursor_pad, nbuk);
  {
    int nchunks = (nnz + CHUNK - 1) / CHUNK;
    hipLaunchKernelGGL(partition_lds_kernel, dim3(nchunks), dim3(256), 0,
                       stream, adj_vals, adj_rows, adj_cols, bcursor_pad, tmp,
                       nnz, nbuk);
  }
  hipLaunchKernelGGL(bucket_sort_kernel, dim3(nbuk), dim3(256), 0, stream, tmp,
                     bbase, edges, row_ptr, N);

  // --- init ego + all_emb block 0 (after build: tmp aliased all_emb) ---
  {
    int total = N * EMB;
    hipLaunchKernelGGL(init_ego_kernel, dim3((total + 255) / 256), dim3(256), 0,
                       stream, user_emb, item_emb, user_sizes, item_sizes, ego,
                       all_emb, n_users, N);
  }

  // --- 3 propagation layers ---
  for (int k = 0; k < N_LAYERS; ++k) {
    hipLaunchKernelGGL(spmm_csr_kernel, dim3((N + 3) / 4), dim3(256), 0, stream,
                       row_ptr, edges, ego, side, N);
    hipLaunchKernelGGL(layer_fused_kernel, dim3(2048), dim3(256), 0, stream,
                       side, ego, W_gc + k * EMB * EMB, b_gc + k * EMB,
                       W_bi + k * EMB * EMB, b_bi + k * EMB, all_emb, N,
                       (k + 1) * EMB);
  }

  hipLaunchKernelGGL(gather_out_kernel, dim3(B, 3), dim3(256), 0, stream,
                     all_emb, users, pos_items, neg_items, (float*)d_out,
                     n_users, B);
}

// Round 8
// 696.028 us; speedup vs baseline: 5.0065x; 1.0147x over previous
//
#include <hip/hip_runtime.h>

#define EMB 64
constexpr int N_LAYERS = 3;
constexpr int OUT_D = EMB * (N_LAYERS + 1);  // 256
constexpr int SUBR = 64;       // rows per bucket
constexpr int RSHIFT = 6;      // log2(SUBR)
constexpr int MAXBUK = 2048;   // supports N <= 131072
constexpr int PAD = 16;        // ints per counter line (64B)
constexpr int CHUNK = 8192;    // edges per partition block

__device__ __forceinline__ float readlane_f(float v, int l) {
  return __int_as_float(__builtin_amdgcn_readlane(__float_as_int(v), l));
}
__device__ __forceinline__ int readlane_i(int v, int l) {
  return __builtin_amdgcn_readlane(v, l);
}
// f32 -> bf16 round-to-nearest-even (finite values)
__device__ __forceinline__ unsigned short f32_to_bf16(float f) {
  unsigned x = __float_as_uint(f);
  return (unsigned short)((x + 0x7FFF + ((x >> 16) & 1)) >> 16);
}
// bf16 bits -> f32 (exact)
__device__ __forceinline__ float bf16_to_f32(unsigned short u) {
  return __uint_as_float(((unsigned)u) << 16);
}

// ego[r][d] = masked embedding; also bf16 shadow + block 0 of all_emb [N][256]
// NOTE: launched AFTER the CSR build because tmp aliases all_emb.
__global__ void init_ego_kernel(const float* __restrict__ ue, const float* __restrict__ ie,
                                const int* __restrict__ usz, const int* __restrict__ isz,
                                float* __restrict__ ego, unsigned short* __restrict__ egobf,
                                float* __restrict__ all_emb, int n_users, int n_total) {
  int idx = blockIdx.x * blockDim.x + threadIdx.x;
  if (idx >= n_total * EMB) return;
  int r = idx >> 6, d = idx & 63;
  float v; int sz;
  if (r < n_users) {
    v = ue[idx];
    sz = usz[r];
  } else {
    int ri = r - n_users;
    v = ie[ri * EMB + d];
    sz = isz[ri];
  }
  v = (d < sz) ? v : 0.0f;
  ego[idx] = v;
  egobf[idx] = f32_to_bf16(v);
  all_emb[(size_t)r * OUT_D + d] = v;
}

// ---------- bucket histogram: LDS-aggregated, padded global flush ----------
__global__ __launch_bounds__(256) void bucket_hist_kernel(const int* __restrict__ rows,
                                                          int* __restrict__ bcnt_pad,
                                                          int nnz, int nbuk) {
  __shared__ int h[MAXBUK];
  for (int i = threadIdx.x; i < nbuk; i += 256) h[i] = 0;
  __syncthreads();
  int i = blockIdx.x * blockDim.x + threadIdx.x;
  int stride = gridDim.x * blockDim.x;
  for (; i < nnz; i += stride) atomicAdd(&h[rows[i] >> RSHIFT], 1);
  __syncthreads();
  for (int b = threadIdx.x; b < nbuk; b += 256)
    if (h[b]) atomicAdd(&bcnt_pad[b * PAD], h[b]);
}

// ---------- exclusive scan of padded counts -> bbase + padded cursors ----------
__global__ __launch_bounds__(512) void bucket_scan_kernel(const int* __restrict__ bcnt_pad,
                                                          int* __restrict__ bbase,
                                                          int* __restrict__ bcursor_pad,
                                                          int nbuk) {
  __shared__ int vals[MAXBUK];
  __shared__ int part[512];
  int t = threadIdx.x;
  for (int i = t; i < nbuk; i += 512) vals[i] = bcnt_pad[i * PAD];
  __syncthreads();
  int per = (nbuk + 511) / 512;
  int s0 = t * per;
  int lsum = 0;
  for (int i = 0; i < per; ++i) {
    int idx = s0 + i;
    if (idx < nbuk) lsum += vals[idx];
  }
  part[t] = lsum;
  __syncthreads();
  if (t == 0) {
    int acc = 0;
    for (int i = 0; i < 512; ++i) {
      int x = part[i];
      part[i] = acc;
      acc += x;
    }
  }
  __syncthreads();
  int run = part[t];
  for (int i = 0; i < per; ++i) {
    int idx = s0 + i;
    if (idx < nbuk) {
      bbase[idx] = run;
      bcursor_pad[idx * PAD] = run;
      run += vals[idx];
    }
  }
  if (t == 511) bbase[nbuk] = run;
}

// ---------- 3-phase LDS-staged partition (re-read, no register staging) ----------
__global__ __launch_bounds__(256) void partition_lds_kernel(
    const float* __restrict__ vals, const int* __restrict__ rows,
    const int* __restrict__ cols, int* __restrict__ bcursor_pad,
    int2* __restrict__ tmp, int nnz, int nbuk) {
  __shared__ int h[MAXBUK];
  __shared__ int cur[MAXBUK];
  for (int i = threadIdx.x; i < nbuk; i += 256) h[i] = 0;
  __syncthreads();
  int lo = blockIdx.x * CHUNK;
  int hi = lo + CHUNK;
  if (hi > nnz) hi = nnz;
  for (int ii = lo + (int)threadIdx.x; ii < hi; ii += 256)
    atomicAdd(&h[rows[ii] >> RSHIFT], 1);
  __syncthreads();
  for (int b = threadIdx.x; b < nbuk; b += 256) {
    int c = h[b];
    cur[b] = c ? atomicAdd(&bcursor_pad[b * PAD], c) : 0;
  }
  __syncthreads();
  for (int ii = lo + (int)threadIdx.x; ii < hi; ii += 256) {
    int r = rows[ii];
    int b = r >> RSHIFT;
    int pos = atomicAdd(&cur[b], 1);
    tmp[pos] = make_int2(__float_as_int(vals[ii]),
                         ((r & (SUBR - 1)) << 17) | cols[ii]);
  }
}

// ---------- per-bucket row sort -> final CSR (edges + row_ptr) ----------
__global__ __launch_bounds__(256) void bucket_sort_kernel(
    const int2* __restrict__ tmp, const int* __restrict__ bbase,
    int2* __restrict__ edges, int* __restrict__ row_ptr, int nrows) {
  __shared__ int h[SUBR];
  __shared__ int ex[SUBR + 1];
  int b = blockIdx.x;
  int s = bbase[b], e = bbase[b + 1];
  if (threadIdx.x < SUBR) h[threadIdx.x] = 0;
  __syncthreads();
  for (int i = s + (int)threadIdx.x; i < e; i += 256)
    atomicAdd(&h[((unsigned)tmp[i].y) >> 17], 1);
  __syncthreads();
  if (threadIdx.x == 0) {
    int acc = 0;
    for (int j = 0; j < SUBR; ++j) {
      ex[j] = acc;
      acc += h[j];
    }
    ex[SUBR] = acc;
  }
  __syncthreads();
  int r0 = b << RSHIFT;
  if (threadIdx.x <= SUBR) {
    int j = threadIdx.x;
    int r = r0 + j;
    if ((j < SUBR && r < nrows) || r == nrows) row_ptr[r] = s + ex[j];
  }
  if (threadIdx.x < SUBR) h[threadIdx.x] = ex[threadIdx.x];  // cursors
  __syncthreads();
  for (int i = s + (int)threadIdx.x; i < e; i += 256) {
    int2 t = tmp[i];
    int rl = ((unsigned)t.y) >> 17;
    int p = atomicAdd(&h[rl], 1);
    edges[s + p] = make_int2(t.x, t.y & 0x1FFFF);
  }
}

// ---------- CSR SpMM: one wave per row, lane = dim, bf16 gathers ----------
__global__ __launch_bounds__(256) void spmm_csr_kernel(
    const int* __restrict__ rp, const int2* __restrict__ edges,
    const unsigned short* __restrict__ egobf, float* __restrict__ side,
    int nrows) {
  int lane = threadIdx.x & 63;
  int r = blockIdx.x * (blockDim.x >> 6) + (threadIdx.x >> 6);
  if (r >= nrows) return;
  int start = rp[r], end = rp[r + 1];
  float acc = 0.0f;
  for (int base = start; base < end; base += 64) {
    int m = end - base;
    if (m > 64) m = 64;
    int2 e = (base + lane < end) ? edges[base + lane] : make_int2(0, 0);
    float v_l = __int_as_float(e.x);
    int c_l = e.y;
    int kk = 0;
    for (; kk + 8 <= m; kk += 8) {
      int c[8];
      float v[8], x[8];
#pragma unroll
      for (int u = 0; u < 8; ++u) {
        c[u] = readlane_i(c_l, kk + u);
        v[u] = readlane_f(v_l, kk + u);
      }
#pragma unroll
      for (int u = 0; u < 8; ++u)
        x[u] = bf16_to_f32(egobf[(size_t)c[u] * EMB + lane]);
#pragma unroll
      for (int u = 0; u < 8; ++u) acc = fmaf(v[u], x[u], acc);
    }
    for (; kk < m; ++kk) {
      int c = readlane_i(c_l, kk);
      float v = readlane_f(v_l, kk);
      acc = fmaf(v, bf16_to_f32(egobf[(size_t)c * EMB + lane]), acc);
    }
  }
  side[(size_t)r * EMB + lane] = acc;
}

__global__ __launch_bounds__(256) void layer_fused_kernel(
    const float* __restrict__ side, float* ego, unsigned short* __restrict__ egobf,
    const float* __restrict__ Wgc, const float* __restrict__ bgc,
    const float* __restrict__ Wbi, const float* __restrict__ bbi,
    float* __restrict__ all_emb, int nrows, int col_off) {
  int lane = threadIdx.x & 63;
  float wgc[EMB], wbi[EMB];
#pragma unroll
  for (int kk = 0; kk < EMB; ++kk) {
    wgc[kk] = Wgc[kk * EMB + lane];
    wbi[kk] = Wbi[kk * EMB + lane];
  }
  float bg = bgc[lane], bb = bbi[lane];
  int wid = blockIdx.x * (blockDim.x >> 6) + (threadIdx.x >> 6);
  int nw = gridDim.x * (blockDim.x >> 6);
  for (int r = wid; r < nrows; r += nw) {
    float s = side[(size_t)r * EMB + lane];
    float e = ego[(size_t)r * EMB + lane];
    float es = e * s;
    float accg = bg, accb = bb;
#pragma unroll
    for (int kk = 0; kk < EMB; ++kk) {
      accg = fmaf(readlane_f(s, kk), wgc[kk], accg);
      accb = fmaf(readlane_f(es, kk), wbi[kk], accb);
    }
    float o = accg + accb;
    o = (o >= 0.0f) ? o : 0.2f * o;
    ego[(size_t)r * EMB + lane] = o;
    egobf[(size_t)r * EMB + lane] = f32_to_bf16(o);
    float sq = o * o;
#pragma unroll
    for (int off = 32; off; off >>= 1) sq += __shfl_xor(sq, off, 64);
    float norm = fmaxf(sqrtf(sq), 1e-12f);
    all_emb[(size_t)r * OUT_D + col_off + lane] = o / norm;
  }
}

__global__ void gather_out_kernel(const float* __restrict__ all_emb,
                                  const int* __restrict__ users,
                                  const int* __restrict__ pos,
                                  const int* __restrict__ neg,
                                  float* __restrict__ out, int n_users, int B) {
  int row = blockIdx.x;
  int sec = blockIdx.y;
  int t = threadIdx.x;
  int src;
  if (sec == 0) src = users[row];
  else if (sec == 1) src = n_users + pos[row];
  else src = n_users + neg[row];
  out[((size_t)sec * B + row) * OUT_D + t] = all_emb[(size_t)src * OUT_D + t];
}

extern "C" void kernel_launch(void* const* d_in, const int* in_sizes, int n_in,
                              void* d_out, int out_size, void* d_ws, size_t ws_size,
                              hipStream_t stream) {
  const float* user_emb = (const float*)d_in[0];
  const float* item_emb = (const float*)d_in[1];
  const float* W_gc = (const float*)d_in[2];
  const float* b_gc = (const float*)d_in[3];
  const float* W_bi = (const float*)d_in[4];
  const float* b_bi = (const float*)d_in[5];
  const float* adj_vals = (const float*)d_in[6];
  const int* adj_rows = (const int*)d_in[7];
  const int* adj_cols = (const int*)d_in[8];
  const int* user_sizes = (const int*)d_in[9];
  const int* item_sizes = (const int*)d_in[10];
  const int* users = (const int*)d_in[11];
  const int* pos_items = (const int*)d_in[12];
  const int* neg_items = (const int*)d_in[13];

  const int n_users = in_sizes[9];
  const int n_items = in_sizes[10];
  const int N = n_users + n_items;
  const int nnz = in_sizes[6];
  const int B = in_sizes[11];
  const int nbuk = (N + SUBR - 1) / SUBR;  // 1563 for N=100000

  // workspace layout:
  // all_emb [N*256]f (tmp int2[nnz] aliases its head during build)
  // | ego [N*64]f | side [N*64]f | row_ptr [N+1]i | bbase [nbuk+1]i |
  // bcnt_pad [nbuk*PAD]i | bcursor_pad [nbuk*PAD]i | (align 8) edges [nnz]int2
  // | egobf [N*64]u16
  float* all_emb = (float*)d_ws;
  float* ego = all_emb + (size_t)N * OUT_D;
  float* side = ego + (size_t)N * EMB;
  int* row_ptr = (int*)(side + (size_t)N * EMB);
  int* bbase = row_ptr + (N + 1);
  int* bcnt_pad = bbase + (nbuk + 1);
  int* bcursor_pad = bcnt_pad + (size_t)nbuk * PAD;
  int2* edges = (int2*)((((uintptr_t)(bcursor_pad + (size_t)nbuk * PAD)) + 7) &
                        ~(uintptr_t)7);
  unsigned short* egobf = (unsigned short*)(edges + nnz);
  int2* tmp = (int2*)all_emb;  // aliased; init_ego runs after the build

  // --- build row-sorted CSR (bucket partition + per-bucket sort) ---
  hipMemsetAsync(bcnt_pad, 0, (size_t)nbuk * PAD * sizeof(int), stream);
  hipLaunchKernelGGL(bucket_hist_kernel, dim3(512), dim3(256), 0, stream,
                     adj_rows, bcnt_pad, nnz, nbuk);
  hipLaunchKernelGGL(bucket_scan_kernel, dim3(1), dim3(512), 0, stream,
                     bcnt_pad, bbase, bcursor_pad, nbuk);
  {
    int nchunks = (nnz + CHUNK - 1) / CHUNK;
    hipLaunchKernelGGL(partition_lds_kernel, dim3(nchunks), dim3(256), 0,
                       stream, adj_vals, adj_rows, adj_cols, bcursor_pad, tmp,
                       nnz, nbuk);
  }
  hipLaunchKernelGGL(bucket_sort_kernel, dim3(nbuk), dim3(256), 0, stream, tmp,
                     bbase, edges, row_ptr, N);

  // --- init ego (+bf16 shadow) + all_emb block 0 ---
  {
    int total = N * EMB;
    hipLaunchKernelGGL(init_ego_kernel, dim3((total + 255) / 256), dim3(256), 0,
                       stream, user_emb, item_emb, user_sizes, item_sizes, ego,
                       egobf, all_emb, n_users, N);
  }

  // --- 3 propagation layers ---
  for (int k = 0; k < N_LAYERS; ++k) {
    hipLaunchKernelGGL(spmm_csr_kernel, dim3((N + 3) / 4), dim3(256), 0, stream,
                       row_ptr, edges, egobf, side, N);
    hipLaunchKernelGGL(layer_fused_kernel, dim3(2048), dim3(256), 0, stream,
                       side, ego, egobf, W_gc + k * EMB * EMB, b_gc + k * EMB,
                       W_bi + k * EMB * EMB, b_bi + k * EMB, all_emb, N,
                       (k + 1) * EMB);
  }

  hipLaunchKernelGGL(gather_out_kernel, dim3(B, 3), dim3(256), 0, stream,
                     all_emb, users, pos_items, neg_items, (float*)d_out,
                     n_users, B);
}

// Round 9
// 681.377 us; speedup vs baseline: 5.1142x; 1.0215x over previous
//
#include <hip/hip_runtime.h>

#define EMB 64
constexpr int N_LAYERS = 3;
constexpr int OUT_D = EMB * (N_LAYERS + 1);  // 256
constexpr int SUBR = 64;       // rows per bucket
constexpr int RSHIFT = 6;      // log2(SUBR)
constexpr int MAXBUK = 2048;   // supports N <= 131072
constexpr int PAD = 16;        // ints per counter line (64B)
constexpr int CHUNK = 4096;    // edges per partition block
constexpr int EPT = CHUNK / 256;  // 16 edges/thread (register-staged)

__device__ __forceinline__ float readlane_f(float v, int l) {
  return __int_as_float(__builtin_amdgcn_readlane(__float_as_int(v), l));
}
__device__ __forceinline__ int readlane_i(int v, int l) {
  return __builtin_amdgcn_readlane(v, l);
}
// f32 -> bf16 round-to-nearest-even (finite values)
__device__ __forceinline__ unsigned short f32_to_bf16(float f) {
  unsigned x = __float_as_uint(f);
  return (unsigned short)((x + 0x7FFF + ((x >> 16) & 1)) >> 16);
}
// bf16 bits -> f32 (exact)
__device__ __forceinline__ float bf16_to_f32(unsigned short u) {
  return __uint_as_float(((unsigned)u) << 16);
}

// ego[r][d] = masked embedding; also bf16 shadow + block 0 of all_emb [N][256]
// NOTE: launched AFTER the CSR build because tmp aliases all_emb.
__global__ void init_ego_kernel(const float* __restrict__ ue, const float* __restrict__ ie,
                                const int* __restrict__ usz, const int* __restrict__ isz,
                                float* __restrict__ ego, unsigned short* __restrict__ egobf,
                                float* __restrict__ all_emb, int n_users, int n_total) {
  int idx = blockIdx.x * blockDim.x + threadIdx.x;
  if (idx >= n_total * EMB) return;
  int r = idx >> 6, d = idx & 63;
  float v; int sz;
  if (r < n_users) {
    v = ue[idx];
    sz = usz[r];
  } else {
    int ri = r - n_users;
    v = ie[ri * EMB + d];
    sz = isz[ri];
  }
  v = (d < sz) ? v : 0.0f;
  ego[idx] = v;
  egobf[idx] = f32_to_bf16(v);
  all_emb[(size_t)r * OUT_D + d] = v;
}

// ---------- bucket histogram: LDS-aggregated, padded global flush ----------
__global__ __launch_bounds__(256) void bucket_hist_kernel(const int* __restrict__ rows,
                                                          int* __restrict__ bcnt_pad,
                                                          int nnz, int nbuk) {
  __shared__ int h[MAXBUK];
  for (int i = threadIdx.x; i < nbuk; i += 256) h[i] = 0;
  __syncthreads();
  int i = blockIdx.x * blockDim.x + threadIdx.x;
  int stride = gridDim.x * blockDim.x;
  for (; i < nnz; i += stride) atomicAdd(&h[rows[i] >> RSHIFT], 1);
  __syncthreads();
  for (int b = threadIdx.x; b < nbuk; b += 256)
    if (h[b]) atomicAdd(&bcnt_pad[b * PAD], h[b]);
}

// ---------- exclusive scan of padded counts -> bbase + padded cursors ----------
__global__ __launch_bounds__(512) void bucket_scan_kernel(const int* __restrict__ bcnt_pad,
                                                          int* __restrict__ bbase,
                                                          int* __restrict__ bcursor_pad,
                                                          int nbuk) {
  __shared__ int vals[MAXBUK];
  __shared__ int part[512];
  int t = threadIdx.x;
  for (int i = t; i < nbuk; i += 512) vals[i] = bcnt_pad[i * PAD];
  __syncthreads();
  int per = (nbuk + 511) / 512;
  int s0 = t * per;
  int lsum = 0;
  for (int i = 0; i < per; ++i) {
    int idx = s0 + i;
    if (idx < nbuk) lsum += vals[idx];
  }
  part[t] = lsum;
  __syncthreads();
  if (t == 0) {
    int acc = 0;
    for (int i = 0; i < 512; ++i) {
      int x = part[i];
      part[i] = acc;
      acc += x;
    }
  }
  __syncthreads();
  int run = part[t];
  for (int i = 0; i < per; ++i) {
    int idx = s0 + i;
    if (idx < nbuk) {
      bbase[idx] = run;
      bcursor_pad[idx * PAD] = run;
      run += vals[idx];
    }
  }
  if (t == 511) bbase[nbuk] = run;
}

// ---------- 3-phase LDS-staged partition (register-staged, CHUNK=4096) ----------
// (R6-measured-good form: WRITE ~26MB; burst writes from register staging +
//  625 resident blocks keep per-(block,bucket) runs line-coalesced in L2.)
__global__ __launch_bounds__(256) void partition_lds_kernel(
    const float* __restrict__ vals, const int* __restrict__ rows,
    const int* __restrict__ cols, int* __restrict__ bcursor_pad,
    int2* __restrict__ tmp, int nnz, int nbuk) {
  __shared__ int h[MAXBUK];
  __shared__ int cur[MAXBUK];
  for (int i = threadIdx.x; i < nbuk; i += 256) h[i] = 0;
  __syncthreads();

  int base = blockIdx.x * CHUNK;
  int rw[EPT], cl[EPT];
  float vl[EPT];
#pragma unroll
  for (int u = 0; u < EPT; ++u) {
    int ii = base + u * 256 + (int)threadIdx.x;
    bool ok = ii < nnz;
    rw[u] = ok ? rows[ii] : -1;
    cl[u] = ok ? cols[ii] : 0;
    vl[u] = ok ? vals[ii] : 0.0f;
    if (ok) atomicAdd(&h[rw[u] >> RSHIFT], 1);
  }
  __syncthreads();
  for (int b = threadIdx.x; b < nbuk; b += 256) {
    int c = h[b];
    cur[b] = c ? atomicAdd(&bcursor_pad[b * PAD], c) : 0;
  }
  __syncthreads();
#pragma unroll
  for (int u = 0; u < EPT; ++u) {
    if (rw[u] >= 0) {
      int b = rw[u] >> RSHIFT;
      int pos = atomicAdd(&cur[b], 1);
      tmp[pos] = make_int2(__float_as_int(vl[u]),
                           ((rw[u] & (SUBR - 1)) << 17) | cl[u]);
    }
  }
}

// ---------- per-bucket row sort -> final CSR (edges + row_ptr) ----------
__global__ __launch_bounds__(256) void bucket_sort_kernel(
    const int2* __restrict__ tmp, const int* __restrict__ bbase,
    int2* __restrict__ edges, int* __restrict__ row_ptr, int nrows) {
  __shared__ int h[SUBR];
  __shared__ int ex[SUBR + 1];
  int b = blockIdx.x;
  int s = bbase[b], e = bbase[b + 1];
  if (threadIdx.x < SUBR) h[threadIdx.x] = 0;
  __syncthreads();
  for (int i = s + (int)threadIdx.x; i < e; i += 256)
    atomicAdd(&h[((unsigned)tmp[i].y) >> 17], 1);
  __syncthreads();
  if (threadIdx.x == 0) {
    int acc = 0;
    for (int j = 0; j < SUBR; ++j) {
      ex[j] = acc;
      acc += h[j];
    }
    ex[SUBR] = acc;
  }
  __syncthreads();
  int r0 = b << RSHIFT;
  if (threadIdx.x <= SUBR) {
    int j = threadIdx.x;
    int r = r0 + j;
    if ((j < SUBR && r < nrows) || r == nrows) row_ptr[r] = s + ex[j];
  }
  if (threadIdx.x < SUBR) h[threadIdx.x] = ex[threadIdx.x];  // cursors
  __syncthreads();
  for (int i = s + (int)threadIdx.x; i < e; i += 256) {
    int2 t = tmp[i];
    int rl = ((unsigned)t.y) >> 17;
    int p = atomicAdd(&h[rl], 1);
    edges[s + p] = make_int2(t.x, t.y & 0x1FFFF);
  }
}

// ---------- CSR SpMM: one wave per row, lane = dim, bf16 gathers ----------
__global__ __launch_bounds__(256) void spmm_csr_kernel(
    const int* __restrict__ rp, const int2* __restrict__ edges,
    const unsigned short* __restrict__ egobf, float* __restrict__ side,
    int nrows) {
  int lane = threadIdx.x & 63;
  int r = blockIdx.x * (blockDim.x >> 6) + (threadIdx.x >> 6);
  if (r >= nrows) return;
  int start = rp[r], end = rp[r + 1];
  float acc = 0.0f;
  for (int base = start; base < end; base += 64) {
    int m = end - base;
    if (m > 64) m = 64;
    int2 e = (base + lane < end) ? edges[base + lane] : make_int2(0, 0);
    float v_l = __int_as_float(e.x);
    int c_l = e.y;
    int kk = 0;
    for (; kk + 8 <= m; kk += 8) {
      int c[8];
      float v[8], x[8];
#pragma unroll
      for (int u = 0; u < 8; ++u) {
        c[u] = readlane_i(c_l, kk + u);
        v[u] = readlane_f(v_l, kk + u);
      }
#pragma unroll
      for (int u = 0; u < 8; ++u)
        x[u] = bf16_to_f32(egobf[(size_t)c[u] * EMB + lane]);
#pragma unroll
      for (int u = 0; u < 8; ++u) acc = fmaf(v[u], x[u], acc);
    }
    for (; kk < m; ++kk) {
      int c = readlane_i(c_l, kk);
      float v = readlane_f(v_l, kk);
      acc = fmaf(v, bf16_to_f32(egobf[(size_t)c * EMB + lane]), acc);
    }
  }
  side[(size_t)r * EMB + lane] = acc;
}

// per row: sum = side@Wgc + bgc ; bi = (ego*side)@Wbi + bbi ;
// ego_new = leaky_relu(sum+bi, 0.2) (UNNORMALIZED -> ego/egobf);
// all_emb[:, col_off:+64] = ego_new / max(||ego_new||, 1e-12)
// 8 independent FMA chains (4 per GEMM) to beat the 4-cyc dep latency.
__global__ __launch_bounds__(256) void layer_fused_kernel(
    const float* __restrict__ side, float* ego, unsigned short* __restrict__ egobf,
    const float* __restrict__ Wgc, const float* __restrict__ bgc,
    const float* __restrict__ Wbi, const float* __restrict__ bbi,
    float* __restrict__ all_emb, int nrows, int col_off) {
  int lane = threadIdx.x & 63;
  float wgc[EMB], wbi[EMB];
#pragma unroll
  for (int kk = 0; kk < EMB; ++kk) {
    wgc[kk] = Wgc[kk * EMB + lane];
    wbi[kk] = Wbi[kk * EMB + lane];
  }
  float bg = bgc[lane], bb = bbi[lane];
  int wid = blockIdx.x * (blockDim.x >> 6) + (threadIdx.x >> 6);
  int nw = gridDim.x * (blockDim.x >> 6);
  for (int r = wid; r < nrows; r += nw) {
    float s = side[(size_t)r * EMB + lane];
    float e = ego[(size_t)r * EMB + lane];
    float es = e * s;
    float g0 = 0.f, g1 = 0.f, g2 = 0.f, g3 = 0.f;
    float h0 = 0.f, h1 = 0.f, h2 = 0.f, h3 = 0.f;
#pragma unroll
    for (int kk = 0; kk < EMB; kk += 4) {
      g0 = fmaf(readlane_f(s, kk + 0), wgc[kk + 0], g0);
      g1 = fmaf(readlane_f(s, kk + 1), wgc[kk + 1], g1);
      g2 = fmaf(readlane_f(s, kk + 2), wgc[kk + 2], g2);
      g3 = fmaf(readlane_f(s, kk + 3), wgc[kk + 3], g3);
      h0 = fmaf(readlane_f(es, kk + 0), wbi[kk + 0], h0);
      h1 = fmaf(readlane_f(es, kk + 1), wbi[kk + 1], h1);
      h2 = fmaf(readlane_f(es, kk + 2), wbi[kk + 2], h2);
      h3 = fmaf(readlane_f(es, kk + 3), wbi[kk + 3], h3);
    }
    float o = (((g0 + g1) + (g2 + g3)) + bg) + (((h0 + h1) + (h2 + h3)) + bb);
    o = (o >= 0.0f) ? o : 0.2f * o;
    ego[(size_t)r * EMB + lane] = o;
    egobf[(size_t)r * EMB + lane] = f32_to_bf16(o);
    float sq = o * o;
#pragma unroll
    for (int off = 32; off; off >>= 1) sq += __shfl_xor(sq, off, 64);
    float norm = fmaxf(sqrtf(sq), 1e-12f);
    all_emb[(size_t)r * OUT_D + col_off + lane] = o / norm;
  }
}

__global__ void gather_out_kernel(const float* __restrict__ all_emb,
                                  const int* __restrict__ users,
                                  const int* __restrict__ pos,
                                  const int* __restrict__ neg,
                                  float* __restrict__ out, int n_users, int B) {
  int row = blockIdx.x;
  int sec = blockIdx.y;
  int t = threadIdx.x;
  int src;
  if (sec == 0) src = users[row];
  else if (sec == 1) src = n_users + pos[row];
  else src = n_users + neg[row];
  out[((size_t)sec * B + row) * OUT_D + t] = all_emb[(size_t)src * OUT_D + t];
}

extern "C" void kernel_launch(void* const* d_in, const int* in_sizes, int n_in,
                              void* d_out, int out_size, void* d_ws, size_t ws_size,
                              hipStream_t stream) {
  const float* user_emb = (const float*)d_in[0];
  const float* item_emb = (const float*)d_in[1];
  const float* W_gc = (const float*)d_in[2];
  const float* b_gc = (const float*)d_in[3];
  const float* W_bi = (const float*)d_in[4];
  const float* b_bi = (const float*)d_in[5];
  const float* adj_vals = (const float*)d_in[6];
  const int* adj_rows = (const int*)d_in[7];
  const int* adj_cols = (const int*)d_in[8];
  const int* user_sizes = (const int*)d_in[9];
  const int* item_sizes = (const int*)d_in[10];
  const int* users = (const int*)d_in[11];
  const int* pos_items = (const int*)d_in[12];
  const int* neg_items = (const int*)d_in[13];

  const int n_users = in_sizes[9];
  const int n_items = in_sizes[10];
  const int N = n_users + n_items;
  const int nnz = in_sizes[6];
  const int B = in_sizes[11];
  const int nbuk = (N + SUBR - 1) / SUBR;  // 1563 for N=100000

  // workspace layout:
  // all_emb [N*256]f (tmp int2[nnz] aliases its head during build)
  // | ego [N*64]f | side [N*64]f | row_ptr [N+1]i | bbase [nbuk+1]i |
  // bcnt_pad [nbuk*PAD]i | bcursor_pad [nbuk*PAD]i | (align 8) edges [nnz]int2
  // | egobf [N*64]u16
  float* all_emb = (float*)d_ws;
  float* ego = all_emb + (size_t)N * OUT_D;
  float* side = ego + (size_t)N * EMB;
  int* row_ptr = (int*)(side + (size_t)N * EMB);
  int* bbase = row_ptr + (N + 1);
  int* bcnt_pad = bbase + (nbuk + 1);
  int* bcursor_pad = bcnt_pad + (size_t)nbuk * PAD;
  int2* edges = (int2*)((((uintptr_t)(bcursor_pad + (size_t)nbuk * PAD)) + 7) &
                        ~(uintptr_t)7);
  unsigned short* egobf = (unsigned short*)(edges + nnz);
  int2* tmp = (int2*)all_emb;  // aliased; init_ego runs after the build

  // --- build row-sorted CSR (bucket partition + per-bucket sort) ---
  hipMemsetAsync(bcnt_pad, 0, (size_t)nbuk * PAD * sizeof(int), stream);
  hipLaunchKernelGGL(bucket_hist_kernel, dim3(512), dim3(256), 0, stream,
                     adj_rows, bcnt_pad, nnz, nbuk);
  hipLaunchKernelGGL(bucket_scan_kernel, dim3(1), dim3(512), 0, stream,
                     bcnt_pad, bbase, bcursor_pad, nbuk);
  {
    int nchunks = (nnz + CHUNK - 1) / CHUNK;
    hipLaunchKernelGGL(partition_lds_kernel, dim3(nchunks), dim3(256), 0,
                       stream, adj_vals, adj_rows, adj_cols, bcursor_pad, tmp,
                       nnz, nbuk);
  }
  hipLaunchKernelGGL(bucket_sort_kernel, dim3(nbuk), dim3(256), 0, stream, tmp,
                     bbase, edges, row_ptr, N);

  // --- init ego (+bf16 shadow) + all_emb block 0 ---
  {
    int total = N * EMB;
    hipLaunchKernelGGL(init_ego_kernel, dim3((total + 255) / 256), dim3(256), 0,
                       stream, user_emb, item_emb, user_sizes, item_sizes, ego,
                       egobf, all_emb, n_users, N);
  }

  // --- 3 propagation layers ---
  for (int k = 0; k < N_LAYERS; ++k) {
    hipLaunchKernelGGL(spmm_csr_kernel, dim3((N + 3) / 4), dim3(256), 0, stream,
                       row_ptr, edges, egobf, side, N);
    hipLaunchKernelGGL(layer_fused_kernel, dim3(4096), dim3(256), 0, stream,
                       side, ego, egobf, W_gc + k * EMB * EMB, b_gc + k * EMB,
                       W_bi + k * EMB * EMB, b_bi + k * EMB, all_emb, N,
                       (k + 1) * EMB);
  }

  hipLaunchKernelGGL(gather_out_kernel, dim3(B, 3), dim3(256), 0, stream,
                     all_emb, users, pos_items, neg_items, (float*)d_out,
                     n_users, B);
}

// Round 11
// 632.444 us; speedup vs baseline: 5.5099x; 1.0774x over previous
//
#include <hip/hip_runtime.h>

#define EMB 64
constexpr int N_LAYERS = 3;
constexpr int OUT_D = EMB * (N_LAYERS + 1);  // 256
constexpr int SUBR = 512;      // rows per bucket (run len 4096/196 ~ 21 edges)
constexpr int RSHIFT = 9;      // log2(SUBR)
constexpr int MAXBUK = 256;    // supports N <= 131072 at SUBR=512
constexpr int PAD = 16;        // ints per counter line (64B)
constexpr int CHUNK = 4096;    // edges per partition block
constexpr int EPT = CHUNK / 256;  // 16 edges/thread (register-staged)

__device__ __forceinline__ float readlane_f(float v, int l) {
  return __int_as_float(__builtin_amdgcn_readlane(__float_as_int(v), l));
}
__device__ __forceinline__ int readlane_i(int v, int l) {
  return __builtin_amdgcn_readlane(v, l);
}
// f32 -> bf16 round-to-nearest-even (finite values)
__device__ __forceinline__ unsigned short f32_to_bf16(float f) {
  unsigned x = __float_as_uint(f);
  return (unsigned short)((x + 0x7FFF + ((x >> 16) & 1)) >> 16);
}
// bf16 bits -> f32 (exact)
__device__ __forceinline__ float bf16_to_f32(unsigned short u) {
  return __uint_as_float(((unsigned)u) << 16);
}

// ego[r][d] = masked embedding; also bf16 shadow + block 0 of all_emb [N][256]
// NOTE: launched AFTER the CSR build because tmp aliases all_emb.
__global__ void init_ego_kernel(const float* __restrict__ ue, const float* __restrict__ ie,
                                const int* __restrict__ usz, const int* __restrict__ isz,
                                float* __restrict__ ego, unsigned short* __restrict__ egobf,
                                float* __restrict__ all_emb, int n_users, int n_total) {
  int idx = blockIdx.x * blockDim.x + threadIdx.x;
  if (idx >= n_total * EMB) return;
  int r = idx >> 6, d = idx & 63;
  float v; int sz;
  if (r < n_users) {
    v = ue[idx];
    sz = usz[r];
  } else {
    int ri = r - n_users;
    v = ie[ri * EMB + d];
    sz = isz[ri];
  }
  v = (d < sz) ? v : 0.0f;
  ego[idx] = v;
  egobf[idx] = f32_to_bf16(v);
  all_emb[(size_t)r * OUT_D + d] = v;
}

// ---------- bucket histogram: LDS-aggregated, padded global flush ----------
__global__ __launch_bounds__(256) void bucket_hist_kernel(const int* __restrict__ rows,
                                                          int* __restrict__ bcnt_pad,
                                                          int nnz, int nbuk) {
  __shared__ int h[MAXBUK];
  for (int i = threadIdx.x; i < nbuk; i += 256) h[i] = 0;
  __syncthreads();
  int i = blockIdx.x * blockDim.x + threadIdx.x;
  int stride = gridDim.x * blockDim.x;
  for (; i < nnz; i += stride) atomicAdd(&h[rows[i] >> RSHIFT], 1);
  __syncthreads();
  for (int b = threadIdx.x; b < nbuk; b += 256)
    if (h[b]) atomicAdd(&bcnt_pad[b * PAD], h[b]);
}

// ---------- exclusive scan of padded counts -> bbase + padded cursors ----------
__global__ __launch_bounds__(512) void bucket_scan_kernel(const int* __restrict__ bcnt_pad,
                                                          int* __restrict__ bbase,
                                                          int* __restrict__ bcursor_pad,
                                                          int nbuk) {
  __shared__ int vals[MAXBUK];
  __shared__ int part[512];
  int t = threadIdx.x;
  for (int i = t; i < nbuk; i += 512) vals[i] = bcnt_pad[i * PAD];
  __syncthreads();
  int per = (nbuk + 511) / 512;
  int s0 = t * per;
  int lsum = 0;
  for (int i = 0; i < per; ++i) {
    int idx = s0 + i;
    if (idx < nbuk) lsum += vals[idx];
  }
  part[t] = lsum;
  __syncthreads();
  if (t == 0) {
    int acc = 0;
    for (int i = 0; i < 512; ++i) {
      int x = part[i];
      part[i] = acc;
      acc += x;
    }
  }
  __syncthreads();
  int run = part[t];
  for (int i = 0; i < per; ++i) {
    int idx = s0 + i;
    if (idx < nbuk) {
      bbase[idx] = run;
      bcursor_pad[idx * PAD] = run;
      run += vals[idx];
    }
  }
  if (t == 511) bbase[nbuk] = run;
}

// ---------- 3-phase LDS-staged partition into 512-row buckets ----------
__global__ __launch_bounds__(256) void partition_lds_kernel(
    const float* __restrict__ vals, const int* __restrict__ rows,
    const int* __restrict__ cols, int* __restrict__ bcursor_pad,
    int2* __restrict__ tmp, int nnz, int nbuk) {
  __shared__ int h[MAXBUK];
  __shared__ int cur[MAXBUK];
  for (int i = threadIdx.x; i < nbuk; i += 256) h[i] = 0;
  __syncthreads();

  int base = blockIdx.x * CHUNK;
  int rw[EPT], cl[EPT];
  float vl[EPT];
#pragma unroll
  for (int u = 0; u < EPT; ++u) {
    int ii = base + u * 256 + (int)threadIdx.x;
    bool ok = ii < nnz;
    rw[u] = ok ? rows[ii] : -1;
    cl[u] = ok ? cols[ii] : 0;
    vl[u] = ok ? vals[ii] : 0.0f;
    if (ok) atomicAdd(&h[rw[u] >> RSHIFT], 1);
  }
  __syncthreads();
  for (int b = threadIdx.x; b < nbuk; b += 256) {
    int c = h[b];
    cur[b] = c ? atomicAdd(&bcursor_pad[b * PAD], c) : 0;
  }
  __syncthreads();
#pragma unroll
  for (int u = 0; u < EPT; ++u) {
    if (rw[u] >= 0) {
      int b = rw[u] >> RSHIFT;
      int pos = atomicAdd(&cur[b], 1);
      tmp[pos] = make_int2(__float_as_int(vl[u]),
                           ((rw[u] & (SUBR - 1)) << 17) | cl[u]);
    }
  }
}

// ---------- per-bucket row sort -> final CSR (edges + row_ptr) ----------
// one block per 512-row bucket (~13K edges, ~104KB window, L2-resident)
__global__ __launch_bounds__(256) void bucket_sort_kernel(
    const int2* __restrict__ tmp, const int* __restrict__ bbase,
    int2* __restrict__ edges, int* __restrict__ row_ptr, int nrows) {
  __shared__ int h[SUBR];
  __shared__ int ex[SUBR + 1];
  int b = blockIdx.x;
  int s = bbase[b], e = bbase[b + 1];
  for (int j = threadIdx.x; j < SUBR; j += 256) h[j] = 0;
  __syncthreads();
  for (int i = s + (int)threadIdx.x; i < e; i += 256)
    atomicAdd(&h[((unsigned)tmp[i].y) >> 17], 1);
  __syncthreads();
  if (threadIdx.x == 0) {
    int acc = 0;
    for (int j = 0; j < SUBR; ++j) {
      ex[j] = acc;
      acc += h[j];
    }
    ex[SUBR] = acc;
  }
  __syncthreads();
  int r0 = b << RSHIFT;
  for (int j = threadIdx.x; j <= SUBR; j += 256) {
    int r = r0 + j;
    if ((j < SUBR && r < nrows) || r == nrows) row_ptr[r] = s + ex[j];
  }
  for (int j = threadIdx.x; j < SUBR; j += 256) h[j] = ex[j];  // cursors
  __syncthreads();
  for (int i = s + (int)threadIdx.x; i < e; i += 256) {
    int2 t = tmp[i];
    int rl = ((unsigned)t.y) >> 17;
    int p = atomicAdd(&h[rl], 1);
    edges[s + p] = make_int2(t.x, t.y & 0x1FFFF);
  }
}

// ---------- CSR SpMM: one wave per row, lane = dim, bf16 gathers ----------
__global__ __launch_bounds__(256) void spmm_csr_kernel(
    const int* __restrict__ rp, const int2* __restrict__ edges,
    const unsigned short* __restrict__ egobf, float* __restrict__ side,
    int nrows) {
  int lane = threadIdx.x & 63;
  int r = blockIdx.x * (blockDim.x >> 6) + (threadIdx.x >> 6);
  if (r >= nrows) return;
  int start = rp[r], end = rp[r + 1];
  float acc = 0.0f;
  for (int base = start; base < end; base += 64) {
    int m = end - base;
    if (m > 64) m = 64;
    int2 e = (base + lane < end) ? edges[base + lane] : make_int2(0, 0);
    float v_l = __int_as_float(e.x);
    int c_l = e.y;
    int kk = 0;
    for (; kk + 8 <= m; kk += 8) {
      int c[8];
      float v[8], x[8];
#pragma unroll
      for (int u = 0; u < 8; ++u) {
        c[u] = readlane_i(c_l, kk + u);
        v[u] = readlane_f(v_l, kk + u);
      }
#pragma unroll
      for (int u = 0; u < 8; ++u)
        x[u] = bf16_to_f32(egobf[(size_t)c[u] * EMB + lane]);
#pragma unroll
      for (int u = 0; u < 8; ++u) acc = fmaf(v[u], x[u], acc);
    }
    for (; kk < m; ++kk) {
      int c = readlane_i(c_l, kk);
      float v = readlane_f(v_l, kk);
      acc = fmaf(v, bf16_to_f32(egobf[(size_t)c * EMB + lane]), acc);
    }
  }
  side[(size_t)r * EMB + lane] = acc;
}

// per row: sum = side@Wgc + bgc ; bi = (ego*side)@Wbi + bbi ;
// ego_new = leaky_relu(sum+bi, 0.2) (UNNORMALIZED -> ego/egobf);
// all_emb[:, col_off:+64] = ego_new / max(||ego_new||, 1e-12)
__global__ __launch_bounds__(256) void layer_fused_kernel(
    const float* __restrict__ side, float* ego, unsigned short* __restrict__ egobf,
    const float* __restrict__ Wgc, const float* __restrict__ bgc,
    const float* __restrict__ Wbi, const float* __restrict__ bbi,
    float* __restrict__ all_emb, int nrows, int col_off) {
  int lane = threadIdx.x & 63;
  float wgc[EMB], wbi[EMB];
#pragma unroll
  for (int kk = 0; kk < EMB; ++kk) {
    wgc[kk] = Wgc[kk * EMB + lane];
    wbi[kk] = Wbi[kk * EMB + lane];
  }
  float bg = bgc[lane], bb = bbi[lane];
  int wid = blockIdx.x * (blockDim.x >> 6) + (threadIdx.x >> 6);
  int nw = gridDim.x * (blockDim.x >> 6);
  for (int r = wid; r < nrows; r += nw) {
    float s = side[(size_t)r * EMB + lane];
    float e = ego[(size_t)r * EMB + lane];
    float es = e * s;
    float g0 = 0.f, g1 = 0.f, g2 = 0.f, g3 = 0.f;
    float h0 = 0.f, h1 = 0.f, h2 = 0.f, h3 = 0.f;
#pragma unroll
    for (int kk = 0; kk < EMB; kk += 4) {
      g0 = fmaf(readlane_f(s, kk + 0), wgc[kk + 0], g0);
      g1 = fmaf(readlane_f(s, kk + 1), wgc[kk + 1], g1);
      g2 = fmaf(readlane_f(s, kk + 2), wgc[kk + 2], g2);
      g3 = fmaf(readlane_f(s, kk + 3), wgc[kk + 3], g3);
      h0 = fmaf(readlane_f(es, kk + 0), wbi[kk + 0], h0);
      h1 = fmaf(readlane_f(es, kk + 1), wbi[kk + 1], h1);
      h2 = fmaf(readlane_f(es, kk + 2), wbi[kk + 2], h2);
      h3 = fmaf(readlane_f(es, kk + 3), wbi[kk + 3], h3);
    }
    float o = (((g0 + g1) + (g2 + g3)) + bg) + (((h0 + h1) + (h2 + h3)) + bb);
    o = (o >= 0.0f) ? o : 0.2f * o;
    ego[(size_t)r * EMB + lane] = o;
    egobf[(size_t)r * EMB + lane] = f32_to_bf16(o);
    float sq = o * o;
#pragma unroll
    for (int off = 32; off; off >>= 1) sq += __shfl_xor(sq, off, 64);
    float norm = fmaxf(sqrtf(sq), 1e-12f);
    all_emb[(size_t)r * OUT_D + col_off + lane] = o / norm;
  }
}

__global__ void gather_out_kernel(const float* __restrict__ all_emb,
                                  const int* __restrict__ users,
                                  const int* __restrict__ pos,
                                  const int* __restrict__ neg,
                                  float* __restrict__ out, int n_users, int B) {
  int row = blockIdx.x;
  int sec = blockIdx.y;
  int t = threadIdx.x;
  int src;
  if (sec == 0) src = users[row];
  else if (sec == 1) src = n_users + pos[row];
  else src = n_users + neg[row];
  out[((size_t)sec * B + row) * OUT_D + t] = all_emb[(size_t)src * OUT_D + t];
}

extern "C" void kernel_launch(void* const* d_in, const int* in_sizes, int n_in,
                              void* d_out, int out_size, void* d_ws, size_t ws_size,
                              hipStream_t stream) {
  const float* user_emb = (const float*)d_in[0];
  const float* item_emb = (const float*)d_in[1];
  const float* W_gc = (const float*)d_in[2];
  const float* b_gc = (const float*)d_in[3];
  const float* W_bi = (const float*)d_in[4];
  const float* b_bi = (const float*)d_in[5];
  const float* adj_vals = (const float*)d_in[6];
  const int* adj_rows = (const int*)d_in[7];
  const int* adj_cols = (const int*)d_in[8];
  const int* user_sizes = (const int*)d_in[9];
  const int* item_sizes = (const int*)d_in[10];
  const int* users = (const int*)d_in[11];
  const int* pos_items = (const int*)d_in[12];
  const int* neg_items = (const int*)d_in[13];

  const int n_users = in_sizes[9];
  const int n_items = in_sizes[10];
  const int N = n_users + n_items;
  const int nnz = in_sizes[6];
  const int B = in_sizes[11];
  const int nbuk = (N + SUBR - 1) / SUBR;  // 196 for N=100000

  // workspace layout:
  // all_emb [N*256]f (tmp int2[nnz] aliases its head during build)
  // | ego [N*64]f | side [N*64]f | row_ptr [N+1]i | bbase [nbuk+1]i |
  // bcnt_pad [nbuk*PAD]i | bcursor_pad [nbuk*PAD]i | (align 8) edges [nnz]int2
  // | egobf [N*64]u16
  float* all_emb = (float*)d_ws;
  float* ego = all_emb + (size_t)N * OUT_D;
  float* side = ego + (size_t)N * EMB;
  int* row_ptr = (int*)(side + (size_t)N * EMB);
  int* bbase = row_ptr + (N + 1);
  int* bcnt_pad = bbase + (nbuk + 1);
  int* bcursor_pad = bcnt_pad + (size_t)nbuk * PAD;
  int2* edges = (int2*)((((uintptr_t)(bcursor_pad + (size_t)nbuk * PAD)) + 7) &
                        ~(uintptr_t)7);
  unsigned short* egobf = (unsigned short*)(edges + nnz);
  int2* tmp = (int2*)all_emb;  // aliased; init_ego runs after the build

  // --- build row-sorted CSR (bucket partition + per-bucket sort) ---
  hipMemsetAsync(bcnt_pad, 0, (size_t)nbuk * PAD * sizeof(int), stream);
  hipLaunchKernelGGL(bucket_hist_kernel, dim3(512), dim3(256), 0, stream,
                     adj_rows, bcnt_pad, nnz, nbuk);
  hipLaunchKernelGGL(bucket_scan_kernel, dim3(1), dim3(512), 0, stream,
                     bcnt_pad, bbase, bcursor_pad, nbuk);
  {
    int nchunks = (nnz + CHUNK - 1) / CHUNK;
    hipLaunchKernelGGL(partition_lds_kernel, dim3(nchunks), dim3(256), 0,
                       stream, adj_vals, adj_rows, adj_cols, bcursor_pad, tmp,
                       nnz, nbuk);
  }
  hipLaunchKernelGGL(bucket_sort_kernel, dim3(nbuk), dim3(256), 0, stream, tmp,
                     bbase, edges, row_ptr, N);

  // --- init ego (+bf16 shadow) + all_emb block 0 ---
  {
    int total = N * EMB;
    hipLaunchKernelGGL(init_ego_kernel, dim3((total + 255) / 256), dim3(256), 0,
                       stream, user_emb, item_emb, user_sizes, item_sizes, ego,
                       egobf, all_emb, n_users, N);
  }

  // --- 3 propagation layers ---
  for (int k = 0; k < N_LAYERS; ++k) {
    hipLaunchKernelGGL(spmm_csr_kernel, dim3((N + 3) / 4), dim3(256), 0, stream,
                       row_ptr, edges, egobf, side, N);
    hipLaunchKernelGGL(layer_fused_kernel, dim3(4096), dim3(256), 0, stream,
                       side, ego, egobf, W_gc + k * EMB * EMB, b_gc + k * EMB,
                       W_bi + k * EMB * EMB, b_bi + k * EMB, all_emb, N,
                       (k + 1) * EMB);
  }

  hipLaunchKernelGGL(gather_out_kernel, dim3(B, 3), dim3(256), 0, stream,
                     all_emb, users, pos_items, neg_items, (float*)d_out,
                     n_users, B);
}